// Round 12
// baseline (109.906 us; speedup 1.0000x reference)
//
#include <hip/hip_runtime.h>

// Kalman filter, STATE=16, MEAS=8, T=500000. H==eye(8,16), exploited throughout.
//
// Round-12: DE-MERGED pipeline. The r9-r11 fused kernel (bodies spin-waiting on
// a flag while one wave runs Riccati) cost ~45us of concurrency tax (kf_mega
// 103us vs ricc-alone 59us + ~8us scan work). Three clean kernels:
//
// kf_ricc (1 wave): 48 exact Riccati steps, single-wave FENCE_LDS instead of
//   barriers (no vmcnt drain). Stage A: M=F*P (Ps in LDS). Stage B: Pb=M*F^T+Q
//   in registers (pre-rotated F^T + quad_perm DPP gathers). readlane GJ solves
//   S K^T = Pb[:8,:]; K_t -> ws; K broadcast via ds_bpermute. Emits A=(I-KH)F,
//   Ktilde, A^32 (row-rotated for DPP mv16 consumers).
// kf_scanA (977 blocks x 256): 16 chunks/block (L=32), whole-chunk z prefetch,
//   local scan from 0 via DPP matvecs (mv16 + folded mv8) -> u_end compact in
//   ws; head group (c==NCHUNK) runs exact t<T0 recursion -> out[0..T0), x0.
// kf_winscanE: 16-entry u_end window w/ A^32 reconstructs xin (span 512 steps;
//   ||A^512|| ~ 2e-5), then re-scans chunk exactly, writes out[T0..TT).
// Path B (small ws): kf_win + kf_scanE via out-slot scratch.

#define TT 500000
#define T0 48
#define L1 32
#define NCHUNK 15624           // ceil((TT-T0)/L1); last chunk = 16 steps
#define NBLKS 977              // ceil((NCHUNK+1)/16)
#define NBLKW 977              // ceil(NCHUNK/16)
#define WINE 16                // window entries; span 16*32 = 512 steps

#define OFF_A    0             // 16x16 rotated  A=(I-KH)F
#define OFF_KR   256           // 16x16 rotated  Ktilde
#define OFF_AL   512           // 16x16 rotated  A^32
#define OFF_X0   768           // 16
#define OFF_KH   784           // T0*128 plain K_t history (ends 6928)
#define OFF_UE   8192          // NCHUNK*16 compact u_end (path A only)

// single-wave LDS fence: order ds_write -> ds_read without draining vmcnt
#define FENCE_LDS() do { \
  asm volatile("s_waitcnt lgkmcnt(0)" ::: "memory"); \
  __builtin_amdgcn_sched_barrier(0); \
} while (0)

__device__ __forceinline__ float rlf(float v, int lane) {
  return __int_as_float(__builtin_amdgcn_readlane(__float_as_int(v), lane));
}
__device__ __forceinline__ float bpermf(int byteaddr, float v) {
  return __int_as_float(__builtin_amdgcn_ds_bpermute(byteaddr, __float_as_int(v)));
}
template<int CTL> __device__ __forceinline__ float dppf(float x) {
  return __int_as_float(__builtin_amdgcn_update_dpp(
      0, __float_as_int(x), CTL, 0xF, 0xF, false));
}
#define QP1 0x39
#define QP2 0x4E
#define QP3 0x93

__device__ __forceinline__ int rot_dir() {
  int r = threadIdx.x & 15;
  int m = __builtin_amdgcn_update_dpp(0, r, 0x121, 0xF, 0xF, false);
  return (m - r) & 15;
}
__device__ __forceinline__ float mv16(const float a[16], float x) {
  float t1=dppf<0x121>(x), t2=dppf<0x122>(x), t3=dppf<0x123>(x), t4=dppf<0x124>(x);
  float t5=dppf<0x125>(x), t6=dppf<0x126>(x), t7=dppf<0x127>(x), t8=dppf<0x128>(x);
  float t9=dppf<0x129>(x), t10=dppf<0x12A>(x),t11=dppf<0x12B>(x),t12=dppf<0x12C>(x);
  float t13=dppf<0x12D>(x),t14=dppf<0x12E>(x),t15=dppf<0x12F>(x);
  float s0 = a[0]*x   + a[4]*t4   + a[8]*t8   + a[12]*t12;
  float s1 = a[1]*t1  + a[5]*t5   + a[9]*t9   + a[13]*t13;
  float s2 = a[2]*t2  + a[6]*t6   + a[10]*t10 + a[14]*t14;
  float s3 = a[3]*t3  + a[7]*t7   + a[11]*t11 + a[15]*t15;
  return (s0 + s1) + (s2 + s3);
}
// folded 8-rotation matvec for the Ktilde product: valid because zt is
// period-8 replicated (lane r holds z_t[r&7]) -> rot s and s+8 coincide.
__device__ __forceinline__ float mv8(const float k8[8], float x) {
  float t1=dppf<0x121>(x), t2=dppf<0x122>(x), t3=dppf<0x123>(x);
  float t4=dppf<0x124>(x), t5=dppf<0x125>(x), t6=dppf<0x126>(x), t7=dppf<0x127>(x);
  float s0 = k8[0]*x  + k8[4]*t4;
  float s1 = k8[1]*t1 + k8[5]*t5;
  float s2 = k8[2]*t2 + k8[6]*t6;
  float s3 = k8[3]*t3 + k8[7]*t7;
  return (s0 + s1) + (s2 + s3);
}
__device__ __forceinline__ void load16(const float* __restrict__ p, int r, float d[16]) {
  #pragma unroll
  for (int j = 0; j < 4; ++j) {
    float4 t = ((const float4*)p)[r*4 + j];
    d[4*j] = t.x; d[4*j+1] = t.y; d[4*j+2] = t.z; d[4*j+3] = t.w;
  }
}
__device__ __forceinline__ void loadkrf(const float* __restrict__ p, int r, float k8[8]) {
  float kr[16];
  load16(p, r, kr);
  #pragma unroll
  for (int i = 0; i < 8; ++i) k8[i] = kr[i] + kr[i + 8];
}
// distribute packed float4 window: zt[j] at lane r = z_t[r&7] (replicated)
__device__ __forceinline__ void zdist(float4 d0, int srcq, bool selhi, bool selodd,
                                      float zt[8]) {
  #pragma unroll
  for (int j = 0; j < 8; ++j) {
    float e0 = __shfl(d0.x, 2*j + srcq, 16);
    float e1 = __shfl(d0.y, 2*j + srcq, 16);
    float e2 = __shfl(d0.z, 2*j + srcq, 16);
    float e3 = __shfl(d0.w, 2*j + srcq, 16);
    float lo = selhi ? e2 : e0;
    float hi = selhi ? e3 : e1;
    zt[j] = selodd ? hi : lo;
  }
}

__global__ __launch_bounds__(64) void kf_ricc(
    const float* __restrict__ Fg, const float* __restrict__ Qg,
    const float* __restrict__ Rg, float* __restrict__ ws)
{
  const int l  = threadIdx.x;
  const int r4 = l >> 2;
  const int q  = l & 3;
  const int c4 = q * 4;
  const int dir = rot_dir();

  __shared__ float Ps[16][20], Pbs[16][20], Ms[16][20];
  __shared__ float KsL[16][8];

  float frow[16];
  #pragma unroll
  for (int k = 0; k < 16; ++k) frow[k] = Fg[r4*16 + k];
  float4 ftr[16];
  #pragma unroll
  for (int d = 0; d < 4; ++d) {
    #pragma unroll
    for (int jp = 0; jp < 4; ++jp) {
      int col = 4*((q + d) & 3) + jp;
      ftr[d*4+jp] = make_float4(Fg[(c4+0)*16 + col], Fg[(c4+1)*16 + col],
                                Fg[(c4+2)*16 + col], Fg[(c4+3)*16 + col]);
    }
  }
  float4 qreg = *(const float4*)&Qg[r4*16 + c4];
  float rcol[8];
  {
    int cc = l & 7;
    #pragma unroll
    for (int i = 0; i < 8; ++i) rcol[i] = Rg[i*8 + cc];
  }
  *(float4*)&Ps[r4][c4] = make_float4(r4==c4 ?1.f:0.f, r4==c4+1?1.f:0.f,
                                      r4==c4+2?1.f:0.f, r4==c4+3?1.f:0.f);
  const int  cidx = (l < 8) ? l : ((l < 24) ? (l - 8) : (l & 7));
  const bool isS  = (l < 8);
  const bool isB  = (l >= 8 && l < 24);
  const int  bj   = l - 8;
  const int  ba   = (8 + r4) << 2;    // bpermute src: lane 8+r4 holds K row r4
  float v[8];
  FENCE_LDS();

  for (int t = 0; t < T0; ++t) {
    // stage A: M[r4][c4..3] = F[r4][:] * P[:, c4..3]
    float m0=0.f,m1=0.f,m2=0.f,m3=0.f;
    #pragma unroll
    for (int k = 0; k < 16; ++k) {
      float4 pk = *(const float4*)&Ps[k][c4];
      float f = frow[k];
      m0 += f*pk.x; m1 += f*pk.y; m2 += f*pk.z; m3 += f*pk.w;
    }
    float g1x=dppf<QP1>(m0), g1y=dppf<QP1>(m1), g1z=dppf<QP1>(m2), g1w=dppf<QP1>(m3);
    float g2x=dppf<QP2>(m0), g2y=dppf<QP2>(m1), g2z=dppf<QP2>(m2), g2w=dppf<QP2>(m3);
    float g3x=dppf<QP3>(m0), g3y=dppf<QP3>(m1), g3z=dppf<QP3>(m2), g3w=dppf<QP3>(m3);
    const float mq[4][4] = {{m0,m1,m2,m3},{g1x,g1y,g1z,g1w},
                            {g2x,g2y,g2z,g2w},{g3x,g3y,g3z,g3w}};
    // stage B: Pb = M * F^T + Q, in registers
    float b0=qreg.x, b1=qreg.y, b2=qreg.z, b3=qreg.w;
    #pragma unroll
    for (int d = 0; d < 4; ++d) {
      #pragma unroll
      for (int jp = 0; jp < 4; ++jp) {
        float mm = mq[d][jp];
        float4 ft = ftr[d*4+jp];
        b0 += mm*ft.x; b1 += mm*ft.y; b2 += mm*ft.z; b3 += mm*ft.w;
      }
    }
    float4 pb = make_float4(b0,b1,b2,b3);
    *(float4*)&Pbs[r4][c4] = pb;
    FENCE_LDS();
    // readlane Gauss-Jordan on [S | B]: solve S X = B, X = K^T
    #pragma unroll
    for (int i = 0; i < 8; ++i)
      v[i] = Pbs[i][cidx] + (isS ? rcol[i] : 0.f);
    #pragma unroll
    for (int p = 0; p < 8; ++p) {
      float piv = rlf(v[p], p);
      float rc  = __builtin_amdgcn_rcpf(piv);
      float fi[8];
      #pragma unroll
      for (int i = 0; i < 8; ++i) fi[i] = rlf(v[i], p) * rc;
      #pragma unroll
      for (int i = 0; i < 8; ++i) if (i != p) v[i] -= fi[i] * v[p];
    }
    {
      float dv[8];
      #pragma unroll
      for (int i = 0; i < 8; ++i) dv[i] = __builtin_amdgcn_rcpf(rlf(v[i], i));
      #pragma unroll
      for (int i = 0; i < 8; ++i) v[i] *= dv[i];
    }
    if (isB) {                       // lane 8+j holds K row j
      #pragma unroll
      for (int i = 0; i < 8; ++i) ws[OFF_KH + t*128 + bj*8 + i] = v[i];
    }
    float kk[8];
    #pragma unroll
    for (int i = 0; i < 8; ++i) kk[i] = bpermf(ba, v[i]);
    // P = Pb - K * Pb[:8,:]
    float4 pn = pb;
    #pragma unroll
    for (int k = 0; k < 8; ++k) {
      float4 pr = *(const float4*)&Pbs[k][c4];
      float kv = kk[k];
      pn.x -= kv*pr.x; pn.y -= kv*pr.y; pn.z -= kv*pr.z; pn.w -= kv*pr.w;
    }
    *(float4*)&Ps[r4][c4] = pn;
    FENCE_LDS();
  }

  // epilogue: K rows to LDS; A = F - K*F[:8,:]
  if (isB) {
    #pragma unroll
    for (int i = 0; i < 8; ++i) KsL[bj][i] = v[i];
  }
  float kk[8];
  #pragma unroll
  for (int i = 0; i < 8; ++i) kk[i] = bpermf(ba, v[i]);
  float a[4];
  #pragma unroll
  for (int j = 0; j < 4; ++j) {
    float s = Fg[r4*16 + c4 + j];
    #pragma unroll
    for (int k = 0; k < 8; ++k) s -= kk[k] * Fg[k*16 + c4 + j];
    a[j] = s;
  }
  *(float4*)&Ms[r4][c4] = make_float4(a[0],a[1],a[2],a[3]);
  #pragma unroll
  for (int j = 0; j < 4; ++j) {
    int c = c4 + j;
    int s = ((c - r4) * dir) & 15;
    ws[OFF_A + r4*16 + s] = a[j];
  }
  FENCE_LDS();
  if (l < 16) {
    #pragma unroll
    for (int s = 0; s < 16; ++s) {
      int c = (l + s*dir) & 15;
      ws[OFF_KR + l*16 + s] = (c < 8) ? KsL[l][c] : 0.f;
    }
  }
  FENCE_LDS();
  // squarings: after n, matrix = A^(2^(n+1)); n==4 -> A^32
  for (int n = 0; n < 5; ++n) {
    float (*src)[20] = (n & 1) ? Pbs : Ms;
    float (*dst)[20] = (n & 1) ? Ms : Pbs;
    float b[4] = {0.f, 0.f, 0.f, 0.f};
    #pragma unroll
    for (int k = 0; k < 16; ++k) {
      float m = src[r4][k];
      const float* p = &src[k][c4];
      b[0] += m*p[0]; b[1] += m*p[1]; b[2] += m*p[2]; b[3] += m*p[3];
    }
    FENCE_LDS();
    dst[r4][c4]=b[0]; dst[r4][c4+1]=b[1]; dst[r4][c4+2]=b[2]; dst[r4][c4+3]=b[3];
    FENCE_LDS();
    if (n == 4) {
      #pragma unroll
      for (int j = 0; j < 4; ++j) {
        int c = c4 + j;
        int s = ((c - r4) * dir) & 15;
        ws[OFF_AL + r4*16 + s] = b[j];
      }
    }
  }
}

// Local scans; WSUE: u_end -> compact ws, else chunk-last out-slot.
// Head group (c==NCHUNK) runs the exact t<T0 recursion.
template<int WSUE>
__global__ __launch_bounds__(256) void kf_scanA(
    const float* __restrict__ z, const float* __restrict__ Fg,
    float* __restrict__ ws, float* __restrict__ out)
{
  const int r = threadIdx.x & 15;
  const int c = blockIdx.x * 16 + (threadIdx.x >> 4);
  if (c > NCHUNK) return;

  if (c == NCHUNK) {
    // exact t<T0 head recursion with time-varying K_t (16-lane group)
    float f[16];
    #pragma unroll
    for (int i = 0; i < 16; ++i) f[i] = Fg[r*16 + i];
    const float4* zb = (const float4*)z + r;
    const float4* kh = (const float4*)&ws[OFF_KH] + r*2;  // [t*32], [t*32+1]
    float x = 0.f;
    float4 d0 = zb[0], d1 = zb[16];
    float4 ka0 = kh[0],  kb0 = kh[1];
    float4 ka1 = kh[32], kb1 = kh[33];
    for (int b = 0; b < T0/8; ++b) {
      float4 nx = (b + 2 < T0/8) ? zb[(b+2)*16] : make_float4(0.f,0.f,0.f,0.f);
      #pragma unroll
      for (int j = 0; j < 8; ++j) {
        const int t = b*8 + j;
        float p0=0.f,p1=0.f,p2=0.f,p3=0.f;
        #pragma unroll
        for (int k = 0; k < 16; k += 4) {
          p0 += f[k]   * __shfl(x, k, 16);
          p1 += f[k+1] * __shfl(x, k+1, 16);
          p2 += f[k+2] * __shfl(x, k+2, 16);
          p3 += f[k+3] * __shfl(x, k+3, 16);
        }
        float xp = (p0+p1)+(p2+p3);
        float z0=__shfl(d0.x,2*j,16),   z1=__shfl(d0.y,2*j,16);
        float z2=__shfl(d0.z,2*j,16),   z3=__shfl(d0.w,2*j,16);
        float z4=__shfl(d0.x,2*j+1,16), z5=__shfl(d0.y,2*j+1,16);
        float z6=__shfl(d0.z,2*j+1,16), z7=__shfl(d0.w,2*j+1,16);
        float acc = xp;
        acc += ka0.x * (z0 - __shfl(xp,0,16));
        acc += ka0.y * (z1 - __shfl(xp,1,16));
        acc += ka0.z * (z2 - __shfl(xp,2,16));
        acc += ka0.w * (z3 - __shfl(xp,3,16));
        acc += kb0.x * (z4 - __shfl(xp,4,16));
        acc += kb0.y * (z5 - __shfl(xp,5,16));
        acc += kb0.z * (z6 - __shfl(xp,6,16));
        acc += kb0.w * (z7 - __shfl(xp,7,16));
        x = acc;
        out[t*16 + r] = x;
        ka0 = ka1; kb0 = kb1;
        if (t + 2 < T0) { ka1 = kh[(t+2)*32]; kb1 = kh[(t+2)*32 + 1]; }
      }
      d0 = d1; d1 = nx;
    }
    ws[OFF_X0 + r] = x;
    return;
  }

  const int s0 = T0 + c * L1;
  const int e  = min(s0 + L1, TT);
  const int nb = (e - s0) >> 3;
  const float4* zb = (const float4*)(z + (size_t)s0 * 8) + r;
  // prefetch whole chunk
  float4 zw0 = zb[0];
  float4 zw1 = (nb > 1) ? zb[16] : make_float4(0.f,0.f,0.f,0.f);
  float4 zw2 = (nb > 2) ? zb[32] : make_float4(0.f,0.f,0.f,0.f);
  float4 zw3 = (nb > 3) ? zb[48] : make_float4(0.f,0.f,0.f,0.f);

  float a[16], krf[8];
  load16(&ws[OFF_A], r, a);
  loadkrf(&ws[OFF_KR], r, krf);
  const int  srcq  = (r >> 2) & 1;
  const bool selhi = (r & 2) != 0, selodd = (r & 1) != 0;
  float u = 0.f;
  float zt[8];
  #pragma unroll
  for (int b = 0; b < 4; ++b) {
    if (b >= nb) break;
    float4 d0 = (b == 0) ? zw0 : (b == 1) ? zw1 : (b == 2) ? zw2 : zw3;
    zdist(d0, srcq, selhi, selodd, zt);
    #pragma unroll
    for (int j = 0; j < 8; ++j)
      u = mv16(a, u) + mv8(krf, zt[j]);
  }
  if (WSUE) ws[OFF_UE + c*16 + r] = u;
  else      out[(size_t)(e - 1)*16 + r] = u;
}

// Path A fused: window-reconstruct xin from compact ws u_end, then scan.
__global__ __launch_bounds__(256) void kf_winscanE(
    const float* __restrict__ z, float* __restrict__ ws,
    float* __restrict__ out)
{
  const int r = threadIdx.x & 15;
  const int c = blockIdx.x * 16 + (threadIdx.x >> 4);
  if (c >= NCHUNK) return;

  float a[16], al[16], krf[8];
  load16(&ws[OFF_A],  r, a);
  load16(&ws[OFF_AL], r, al);
  loadkrf(&ws[OFF_KR], r, krf);

  const int jlo = (c - WINE < -1) ? -1 : (c - WINE);
  float v = 0.f;
  float nxt = (jlo < 0) ? ws[OFF_X0 + r] : ws[OFF_UE + jlo*16 + r];
  for (int j = jlo; j < c; ++j) {
    float cur = nxt;
    int jn = j + 1;
    nxt = (jn < c) ? ws[OFF_UE + jn*16 + r] : 0.f;
    v = mv16(al, v) + cur;
  }

  const int s0 = T0 + c * L1;
  const int e  = min(s0 + L1, TT);
  const int nb = (e - s0) >> 3;
  const float4* zb = (const float4*)(z + (size_t)s0 * 8) + r;
  float u = v;
  const int  srcq  = (r >> 2) & 1;
  const bool selhi = (r & 2) != 0, selodd = (r & 1) != 0;

  float4 d0 = zb[0];
  float4 d1 = (nb > 1) ? zb[16] : make_float4(0.f,0.f,0.f,0.f);
  for (int b = 0; b < nb; ++b) {
    float4 nx = (b + 2 < nb) ? zb[(b+2)*16] : make_float4(0.f,0.f,0.f,0.f);
    const int tb = s0 + b*8;
    float zt[8];
    zdist(d0, srcq, selhi, selodd, zt);
    #pragma unroll
    for (int j = 0; j < 8; ++j) {
      u = mv16(a, u) + mv8(krf, zt[j]);
      out[(size_t)(tb + j)*16 + r] = u;
    }
    d0 = d1; d1 = nx;
  }
}

// Path B: window from out-slots -> xin at chunk-first slot.
__global__ __launch_bounds__(256) void kf_win(
    float* __restrict__ ws, float* __restrict__ out)
{
  const int r = threadIdx.x & 15;
  const int i = blockIdx.x * 16 + (threadIdx.x >> 4);
  if (i >= NCHUNK) return;
  float al[16];
  load16(&ws[OFF_AL], r, al);
  const int jlo = (i - WINE < -1) ? -1 : (i - WINE);
  float v = 0.f;
  float nxt = (jlo < 0) ? ws[OFF_X0 + r]
                        : out[(size_t)(T0 + jlo*L1 + (L1-1))*16 + r];
  for (int j = jlo; j < i; ++j) {
    float cur = nxt;
    int jn = j + 1;
    nxt = (jn < i) ? out[(size_t)(T0 + jn*L1 + (L1-1))*16 + r] : 0.f;
    v = mv16(al, v) + cur;
  }
  out[(size_t)(T0 + i*L1)*16 + r] = v;
}

// Path B: exact re-scan from xin.
__global__ __launch_bounds__(256) void kf_scanE(
    const float* __restrict__ z, float* __restrict__ ws,
    float* __restrict__ out)
{
  const int r = threadIdx.x & 15;
  const int c = blockIdx.x * 16 + (threadIdx.x >> 4);
  if (c >= NCHUNK) return;

  float a[16], krf[8];
  load16(&ws[OFF_A], r, a);
  loadkrf(&ws[OFF_KR], r, krf);
  const int s0 = T0 + c * L1;
  const int e  = min(s0 + L1, TT);
  const int nb = (e - s0) >> 3;
  const float4* zb = (const float4*)(z + (size_t)s0 * 8) + r;
  float u = out[(size_t)s0*16 + r];
  const int  srcq  = (r >> 2) & 1;
  const bool selhi = (r & 2) != 0, selodd = (r & 1) != 0;

  float4 d0 = zb[0];
  float4 d1 = (nb > 1) ? zb[16] : make_float4(0.f,0.f,0.f,0.f);
  for (int b = 0; b < nb; ++b) {
    float4 nx = (b + 2 < nb) ? zb[(b+2)*16] : make_float4(0.f,0.f,0.f,0.f);
    const int tb = s0 + b*8;
    float zt[8];
    zdist(d0, srcq, selhi, selodd, zt);
    #pragma unroll
    for (int j = 0; j < 8; ++j) {
      u = mv16(a, u) + mv8(krf, zt[j]);
      out[(size_t)(tb + j)*16 + r] = u;
    }
    d0 = d1; d1 = nx;
  }
}

extern "C" void kernel_launch(void* const* d_in, const int* in_sizes, int n_in,
                              void* d_out, int out_size, void* d_ws, size_t ws_size,
                              hipStream_t stream) {
  const float* z  = (const float*)d_in[0];
  const float* Fg = (const float*)d_in[1];
  const float* Qg = (const float*)d_in[3];
  const float* Rg = (const float*)d_in[4];
  float* out = (float*)d_out;
  float* ws  = (float*)d_ws;

  kf_ricc<<<1, 64, 0, stream>>>(Fg, Qg, Rg, ws);
  const size_t need = (size_t)(OFF_UE + NCHUNK*16) * sizeof(float);
  if (ws_size >= need) {
    kf_scanA<1><<<NBLKS, 256, 0, stream>>>(z, Fg, ws, out);
    kf_winscanE<<<NBLKW, 256, 0, stream>>>(z, ws, out);
  } else {
    kf_scanA<0><<<NBLKS, 256, 0, stream>>>(z, Fg, ws, out);
    kf_win<<<NBLKW, 256, 0, stream>>>(ws, out);
    kf_scanE<<<NBLKW, 256, 0, stream>>>(z, ws, out);
  }
}

// Round 13
// 99.492 us; speedup vs baseline: 1.1047x; 1.1047x over previous
//
#include <hip/hip_runtime.h>

// Kalman filter, STATE=16, MEAS=8, T=500000. H==eye(8,16), exploited throughout.
//
// Round-13: the scan tail is VALU-ISSUE-bound (500k steps x ~59 wave-inst x
// 2cy = 48us). Cut instructions/step 59 -> ~30:
//  (a) v_fmac_f32_dpp / v_mul_f32_dpp fuse rotation+FMA (VOP2 DPP); DPP
//      sources are kept >=2 VALU insts old via a dummy-operand dependency.
//  (b) z loaded directly in replicated layout (lane r reads z[t*8+(r&7)]),
//      killing the 4-bpermute zdist per step; 32 loads prefetched per chunk.
//
// kf_ricc (1 wave): unchanged r12 structure (57us, latency-bound).
// kf_scanA: per-chunk (L=32) local scans -> u_end; head group -> out[0..T0).
// kf_winscanE: 16-entry u_end window w/ A^32 -> xin (span 512; ||A^512||~2e-5),
//   then exact re-scan writing out. Path B: kf_win + kf_scanE.

#define TT 500000
#define T0 48
#define L1 32
#define NCHUNK 15624           // ceil((TT-T0)/L1); last chunk = 16 steps
#define NBLKS 977              // ceil((NCHUNK+1)/16)
#define NBLKW 977              // ceil(NCHUNK/16)
#define WINE 16                // window entries; span 16*32 = 512 steps

#define OFF_A    0             // 16x16 rotated  A=(I-KH)F
#define OFF_KR   256           // 16x16 rotated  Ktilde
#define OFF_AL   512           // 16x16 rotated  A^32
#define OFF_X0   768           // 16
#define OFF_KH   784           // T0*128 plain K_t history (ends 6928)
#define OFF_UE   8192          // NCHUNK*16 compact u_end (path A only)

// single-wave LDS fence: order ds_write -> ds_read without draining vmcnt
#define FENCE_LDS() do { \
  asm volatile("s_waitcnt lgkmcnt(0)" ::: "memory"); \
  __builtin_amdgcn_sched_barrier(0); \
} while (0)

// DPP-fused FMA: d += rot_S(x) * a.  dep forces scheduling after `dep` is
// computed so the DPP source x is >=2 VALU insts old (DPP read-after-VALU-
// write hazard). row_ror rows are 16 lanes = our group size.
#define FMACDPP(d, x, a, S) \
  asm("v_fmac_f32_dpp %0, %1, %2 row_ror:" #S " row_mask:0xf bank_mask:0xf" \
      : "+v"(d) : "v"(x), "v"(a))
#define MULDPPD(d, x, a, dep, S) \
  asm("v_mul_f32_dpp %0, %1, %2 row_ror:" #S " row_mask:0xf bank_mask:0xf" \
      : "=v"(d) : "v"(x), "v"(a), "v"(dep))

__device__ __forceinline__ float rlf(float v, int lane) {
  return __int_as_float(__builtin_amdgcn_readlane(__float_as_int(v), lane));
}
__device__ __forceinline__ float bpermf(int byteaddr, float v) {
  return __int_as_float(__builtin_amdgcn_ds_bpermute(byteaddr, __float_as_int(v)));
}
template<int CTL> __device__ __forceinline__ float dppf(float x) {
  return __int_as_float(__builtin_amdgcn_update_dpp(
      0, __float_as_int(x), CTL, 0xF, 0xF, false));
}
#define QP1 0x39
#define QP2 0x4E
#define QP3 0x93

__device__ __forceinline__ int rot_dir() {
  int r = threadIdx.x & 15;
  int m = __builtin_amdgcn_update_dpp(0, r, 0x121, 0xF, 0xF, false);
  return (m - r) & 15;
}

// y[r] = sum_k A[r][k] x[k], rotated storage a[s] = A[r][(r+s*dir)&15]
__device__ __forceinline__ float mv16(const float a[16], float x) {
  float s0 = a[0] * x;          // spacer: 1 VALU between x-write and first DPP
  float s1, s2, s3;
  MULDPPD(s1, x, a[1], s0, 1);
  MULDPPD(s2, x, a[2], s0, 2);
  MULDPPD(s3, x, a[3], s0, 3);
  FMACDPP(s0, x, a[4], 4);   FMACDPP(s1, x, a[5], 5);
  FMACDPP(s2, x, a[6], 6);   FMACDPP(s3, x, a[7], 7);
  FMACDPP(s0, x, a[8], 8);   FMACDPP(s1, x, a[9], 9);
  FMACDPP(s2, x, a[10], 10); FMACDPP(s3, x, a[11], 11);
  FMACDPP(s0, x, a[12], 12); FMACDPP(s1, x, a[13], 13);
  FMACDPP(s2, x, a[14], 14); FMACDPP(s3, x, a[15], 15);
  return (s0 + s1) + (s2 + s3);
}

// u' = A u + Ktilde z_t, fused. z is period-8 replicated (lane r holds
// z_t[r&7]) so the Ktilde matvec folds to 8 rotations (k8[s]=kr[s]+kr[s+8]).
__device__ __forceinline__ float stepAK(const float a[16], const float k8[8],
                                        float u, float zv) {
  float s0 = __builtin_fmaf(k8[0], zv, a[0] * u);   // 2 VALU spacer
  float s1, s2, s3;
  MULDPPD(s1, u, a[1], s0, 1);
  MULDPPD(s2, u, a[2], s0, 2);
  MULDPPD(s3, u, a[3], s0, 3);
  FMACDPP(s0, u, a[4], 4);   FMACDPP(s1, u, a[5], 5);
  FMACDPP(s2, u, a[6], 6);   FMACDPP(s3, u, a[7], 7);
  FMACDPP(s0, u, a[8], 8);   FMACDPP(s1, u, a[9], 9);
  FMACDPP(s2, u, a[10], 10); FMACDPP(s3, u, a[11], 11);
  FMACDPP(s0, u, a[12], 12); FMACDPP(s1, u, a[13], 13);
  FMACDPP(s2, u, a[14], 14); FMACDPP(s3, u, a[15], 15);
  FMACDPP(s1, zv, k8[1], 1); FMACDPP(s2, zv, k8[2], 2);
  FMACDPP(s3, zv, k8[3], 3); FMACDPP(s0, zv, k8[4], 4);
  FMACDPP(s1, zv, k8[5], 5); FMACDPP(s2, zv, k8[6], 6);
  FMACDPP(s3, zv, k8[7], 7);
  return (s0 + s1) + (s2 + s3);
}

__device__ __forceinline__ void load16(const float* __restrict__ p, int r, float d[16]) {
  #pragma unroll
  for (int j = 0; j < 4; ++j) {
    float4 t = ((const float4*)p)[r*4 + j];
    d[4*j] = t.x; d[4*j+1] = t.y; d[4*j+2] = t.z; d[4*j+3] = t.w;
  }
}
__device__ __forceinline__ void loadkrf(const float* __restrict__ p, int r, float k8[8]) {
  float kr[16];
  load16(p, r, kr);
  #pragma unroll
  for (int i = 0; i < 8; ++i) k8[i] = kr[i] + kr[i + 8];
}
// replicated z prefetch: zr[t] = z[(s0+t)*8 + (r&7)], clamped at the tail
__device__ __forceinline__ void loadz(const float* __restrict__ z, int s0_,
                                      int r, float zr[L1]) {
  const float* zp = z + (size_t)s0_ * 8 + (r & 7);
  #pragma unroll
  for (int t = 0; t < L1; ++t) {
    const float* q = (s0_ + t < TT) ? (zp + t * 8) : z;
    zr[t] = *q;
  }
}

__global__ __launch_bounds__(64) void kf_ricc(
    const float* __restrict__ Fg, const float* __restrict__ Qg,
    const float* __restrict__ Rg, float* __restrict__ ws)
{
  const int l  = threadIdx.x;
  const int r4 = l >> 2;
  const int q  = l & 3;
  const int c4 = q * 4;
  const int dir = rot_dir();

  __shared__ float Ps[16][20], Pbs[16][20], Ms[16][20];
  __shared__ float KsL[16][8];

  float frow[16];
  #pragma unroll
  for (int k = 0; k < 16; ++k) frow[k] = Fg[r4*16 + k];
  float4 ftr[16];
  #pragma unroll
  for (int d = 0; d < 4; ++d) {
    #pragma unroll
    for (int jp = 0; jp < 4; ++jp) {
      int col = 4*((q + d) & 3) + jp;
      ftr[d*4+jp] = make_float4(Fg[(c4+0)*16 + col], Fg[(c4+1)*16 + col],
                                Fg[(c4+2)*16 + col], Fg[(c4+3)*16 + col]);
    }
  }
  float4 qreg = *(const float4*)&Qg[r4*16 + c4];
  float rcol[8];
  {
    int cc = l & 7;
    #pragma unroll
    for (int i = 0; i < 8; ++i) rcol[i] = Rg[i*8 + cc];
  }
  *(float4*)&Ps[r4][c4] = make_float4(r4==c4 ?1.f:0.f, r4==c4+1?1.f:0.f,
                                      r4==c4+2?1.f:0.f, r4==c4+3?1.f:0.f);
  const int  cidx = (l < 8) ? l : ((l < 24) ? (l - 8) : (l & 7));
  const bool isS  = (l < 8);
  const bool isB  = (l >= 8 && l < 24);
  const int  bj   = l - 8;
  const int  ba   = (8 + r4) << 2;    // bpermute src: lane 8+r4 holds K row r4
  float v[8];
  FENCE_LDS();

  for (int t = 0; t < T0; ++t) {
    // stage A: M[r4][c4..3] = F[r4][:] * P[:, c4..3]
    float m0=0.f,m1=0.f,m2=0.f,m3=0.f;
    #pragma unroll
    for (int k = 0; k < 16; ++k) {
      float4 pk = *(const float4*)&Ps[k][c4];
      float f = frow[k];
      m0 += f*pk.x; m1 += f*pk.y; m2 += f*pk.z; m3 += f*pk.w;
    }
    float g1x=dppf<QP1>(m0), g1y=dppf<QP1>(m1), g1z=dppf<QP1>(m2), g1w=dppf<QP1>(m3);
    float g2x=dppf<QP2>(m0), g2y=dppf<QP2>(m1), g2z=dppf<QP2>(m2), g2w=dppf<QP2>(m3);
    float g3x=dppf<QP3>(m0), g3y=dppf<QP3>(m1), g3z=dppf<QP3>(m2), g3w=dppf<QP3>(m3);
    const float mq[4][4] = {{m0,m1,m2,m3},{g1x,g1y,g1z,g1w},
                            {g2x,g2y,g2z,g2w},{g3x,g3y,g3z,g3w}};
    // stage B: Pb = M * F^T + Q, in registers
    float b0=qreg.x, b1=qreg.y, b2=qreg.z, b3=qreg.w;
    #pragma unroll
    for (int d = 0; d < 4; ++d) {
      #pragma unroll
      for (int jp = 0; jp < 4; ++jp) {
        float mm = mq[d][jp];
        float4 ft = ftr[d*4+jp];
        b0 += mm*ft.x; b1 += mm*ft.y; b2 += mm*ft.z; b3 += mm*ft.w;
      }
    }
    float4 pb = make_float4(b0,b1,b2,b3);
    *(float4*)&Pbs[r4][c4] = pb;
    FENCE_LDS();
    // readlane Gauss-Jordan on [S | B]: solve S X = B, X = K^T
    #pragma unroll
    for (int i = 0; i < 8; ++i)
      v[i] = Pbs[i][cidx] + (isS ? rcol[i] : 0.f);
    #pragma unroll
    for (int p = 0; p < 8; ++p) {
      float piv = rlf(v[p], p);
      float rc  = __builtin_amdgcn_rcpf(piv);
      float fi[8];
      #pragma unroll
      for (int i = 0; i < 8; ++i) fi[i] = rlf(v[i], p) * rc;
      #pragma unroll
      for (int i = 0; i < 8; ++i) if (i != p) v[i] -= fi[i] * v[p];
    }
    {
      float dv[8];
      #pragma unroll
      for (int i = 0; i < 8; ++i) dv[i] = __builtin_amdgcn_rcpf(rlf(v[i], i));
      #pragma unroll
      for (int i = 0; i < 8; ++i) v[i] *= dv[i];
    }
    if (isB) {                       // lane 8+j holds K row j
      #pragma unroll
      for (int i = 0; i < 8; ++i) ws[OFF_KH + t*128 + bj*8 + i] = v[i];
    }
    float kk[8];
    #pragma unroll
    for (int i = 0; i < 8; ++i) kk[i] = bpermf(ba, v[i]);
    // P = Pb - K * Pb[:8,:]
    float4 pn = pb;
    #pragma unroll
    for (int k = 0; k < 8; ++k) {
      float4 pr = *(const float4*)&Pbs[k][c4];
      float kv = kk[k];
      pn.x -= kv*pr.x; pn.y -= kv*pr.y; pn.z -= kv*pr.z; pn.w -= kv*pr.w;
    }
    *(float4*)&Ps[r4][c4] = pn;
    FENCE_LDS();
  }

  // epilogue: K rows to LDS; A = F - K*F[:8,:]
  if (isB) {
    #pragma unroll
    for (int i = 0; i < 8; ++i) KsL[bj][i] = v[i];
  }
  float kk[8];
  #pragma unroll
  for (int i = 0; i < 8; ++i) kk[i] = bpermf(ba, v[i]);
  float a[4];
  #pragma unroll
  for (int j = 0; j < 4; ++j) {
    float s = Fg[r4*16 + c4 + j];
    #pragma unroll
    for (int k = 0; k < 8; ++k) s -= kk[k] * Fg[k*16 + c4 + j];
    a[j] = s;
  }
  *(float4*)&Ms[r4][c4] = make_float4(a[0],a[1],a[2],a[3]);
  #pragma unroll
  for (int j = 0; j < 4; ++j) {
    int c = c4 + j;
    int s = ((c - r4) * dir) & 15;
    ws[OFF_A + r4*16 + s] = a[j];
  }
  FENCE_LDS();
  if (l < 16) {
    #pragma unroll
    for (int s = 0; s < 16; ++s) {
      int c = (l + s*dir) & 15;
      ws[OFF_KR + l*16 + s] = (c < 8) ? KsL[l][c] : 0.f;
    }
  }
  FENCE_LDS();
  // squarings: after n, matrix = A^(2^(n+1)); n==4 -> A^32
  for (int n = 0; n < 5; ++n) {
    float (*src)[20] = (n & 1) ? Pbs : Ms;
    float (*dst)[20] = (n & 1) ? Ms : Pbs;
    float b[4] = {0.f, 0.f, 0.f, 0.f};
    #pragma unroll
    for (int k = 0; k < 16; ++k) {
      float m = src[r4][k];
      const float* p = &src[k][c4];
      b[0] += m*p[0]; b[1] += m*p[1]; b[2] += m*p[2]; b[3] += m*p[3];
    }
    FENCE_LDS();
    dst[r4][c4]=b[0]; dst[r4][c4+1]=b[1]; dst[r4][c4+2]=b[2]; dst[r4][c4+3]=b[3];
    FENCE_LDS();
    if (n == 4) {
      #pragma unroll
      for (int j = 0; j < 4; ++j) {
        int c = c4 + j;
        int s = ((c - r4) * dir) & 15;
        ws[OFF_AL + r4*16 + s] = b[j];
      }
    }
  }
}

// Local scans; WSUE: u_end -> compact ws, else chunk-last out-slot.
// Head group (c==NCHUNK) runs the exact t<T0 recursion.
template<int WSUE>
__global__ __launch_bounds__(256) void kf_scanA(
    const float* __restrict__ z, const float* __restrict__ Fg,
    float* __restrict__ ws, float* __restrict__ out)
{
  const int r = threadIdx.x & 15;
  const int c = blockIdx.x * 16 + (threadIdx.x >> 4);
  if (c > NCHUNK) return;

  if (c == NCHUNK) {
    // exact t<T0 head recursion with time-varying K_t (16-lane group)
    float f[16];
    #pragma unroll
    for (int i = 0; i < 16; ++i) f[i] = Fg[r*16 + i];
    const float4* zb = (const float4*)z + r;
    const float4* kh = (const float4*)&ws[OFF_KH] + r*2;  // [t*32], [t*32+1]
    float x = 0.f;
    float4 d0 = zb[0], d1 = zb[16];
    float4 ka0 = kh[0],  kb0 = kh[1];
    float4 ka1 = kh[32], kb1 = kh[33];
    for (int b = 0; b < T0/8; ++b) {
      float4 nx = (b + 2 < T0/8) ? zb[(b+2)*16] : make_float4(0.f,0.f,0.f,0.f);
      #pragma unroll
      for (int j = 0; j < 8; ++j) {
        const int t = b*8 + j;
        float p0=0.f,p1=0.f,p2=0.f,p3=0.f;
        #pragma unroll
        for (int k = 0; k < 16; k += 4) {
          p0 += f[k]   * __shfl(x, k, 16);
          p1 += f[k+1] * __shfl(x, k+1, 16);
          p2 += f[k+2] * __shfl(x, k+2, 16);
          p3 += f[k+3] * __shfl(x, k+3, 16);
        }
        float xp = (p0+p1)+(p2+p3);
        float z0=__shfl(d0.x,2*j,16),   z1=__shfl(d0.y,2*j,16);
        float z2=__shfl(d0.z,2*j,16),   z3=__shfl(d0.w,2*j,16);
        float z4=__shfl(d0.x,2*j+1,16), z5=__shfl(d0.y,2*j+1,16);
        float z6=__shfl(d0.z,2*j+1,16), z7=__shfl(d0.w,2*j+1,16);
        float acc = xp;
        acc += ka0.x * (z0 - __shfl(xp,0,16));
        acc += ka0.y * (z1 - __shfl(xp,1,16));
        acc += ka0.z * (z2 - __shfl(xp,2,16));
        acc += ka0.w * (z3 - __shfl(xp,3,16));
        acc += kb0.x * (z4 - __shfl(xp,4,16));
        acc += kb0.y * (z5 - __shfl(xp,5,16));
        acc += kb0.z * (z6 - __shfl(xp,6,16));
        acc += kb0.w * (z7 - __shfl(xp,7,16));
        x = acc;
        out[t*16 + r] = x;
        ka0 = ka1; kb0 = kb1;
        if (t + 2 < T0) { ka1 = kh[(t+2)*32]; kb1 = kh[(t+2)*32 + 1]; }
      }
      d0 = d1; d1 = nx;
    }
    ws[OFF_X0 + r] = x;
    return;
  }

  const int s0_ = T0 + c * L1;
  const int len = min(s0_ + L1, TT) - s0_;
  float zr[L1];
  loadz(z, s0_, r, zr);
  float a[16], krf[8];
  load16(&ws[OFF_A], r, a);
  loadkrf(&ws[OFF_KR], r, krf);
  float u = 0.f;
  #pragma unroll
  for (int t = 0; t < L1; ++t) {
    if (t >= len) break;
    u = stepAK(a, krf, u, zr[t]);
  }
  if (WSUE) ws[OFF_UE + c*16 + r] = u;
  else      out[(size_t)(s0_ + len - 1)*16 + r] = u;
}

// Path A fused: window-reconstruct xin from compact ws u_end, then scan.
__global__ __launch_bounds__(256) void kf_winscanE(
    const float* __restrict__ z, float* __restrict__ ws,
    float* __restrict__ out)
{
  const int r = threadIdx.x & 15;
  const int c = blockIdx.x * 16 + (threadIdx.x >> 4);
  if (c >= NCHUNK) return;

  const int s0_ = T0 + c * L1;
  const int len = min(s0_ + L1, TT) - s0_;
  float zr[L1];
  loadz(z, s0_, r, zr);

  float a[16], al[16], krf[8];
  load16(&ws[OFF_A],  r, a);
  load16(&ws[OFF_AL], r, al);
  loadkrf(&ws[OFF_KR], r, krf);

  const int jlo = (c - WINE < -1) ? -1 : (c - WINE);
  float v = 0.f;
  float nxt = (jlo < 0) ? ws[OFF_X0 + r] : ws[OFF_UE + jlo*16 + r];
  for (int j = jlo; j < c; ++j) {
    float cur = nxt;
    int jn = j + 1;
    nxt = (jn < c) ? ws[OFF_UE + jn*16 + r] : 0.f;
    v = mv16(al, v) + cur;
  }

  float u = v;
  #pragma unroll
  for (int t = 0; t < L1; ++t) {
    if (t >= len) break;
    u = stepAK(a, krf, u, zr[t]);
    out[(size_t)(s0_ + t)*16 + r] = u;
  }
}

// Path B: window from out-slots -> xin at chunk-first slot.
__global__ __launch_bounds__(256) void kf_win(
    float* __restrict__ ws, float* __restrict__ out)
{
  const int r = threadIdx.x & 15;
  const int i = blockIdx.x * 16 + (threadIdx.x >> 4);
  if (i >= NCHUNK) return;
  float al[16];
  load16(&ws[OFF_AL], r, al);
  const int jlo = (i - WINE < -1) ? -1 : (i - WINE);
  float v = 0.f;
  float nxt = (jlo < 0) ? ws[OFF_X0 + r]
                        : out[(size_t)(T0 + jlo*L1 + (L1-1))*16 + r];
  for (int j = jlo; j < i; ++j) {
    float cur = nxt;
    int jn = j + 1;
    nxt = (jn < i) ? out[(size_t)(T0 + jn*L1 + (L1-1))*16 + r] : 0.f;
    v = mv16(al, v) + cur;
  }
  out[(size_t)(T0 + i*L1)*16 + r] = v;
}

// Path B: exact re-scan from xin.
__global__ __launch_bounds__(256) void kf_scanE(
    const float* __restrict__ z, float* __restrict__ ws,
    float* __restrict__ out)
{
  const int r = threadIdx.x & 15;
  const int c = blockIdx.x * 16 + (threadIdx.x >> 4);
  if (c >= NCHUNK) return;

  const int s0_ = T0 + c * L1;
  const int len = min(s0_ + L1, TT) - s0_;
  float zr[L1];
  loadz(z, s0_, r, zr);
  float a[16], krf[8];
  load16(&ws[OFF_A], r, a);
  loadkrf(&ws[OFF_KR], r, krf);
  float u = out[(size_t)s0_*16 + r];
  #pragma unroll
  for (int t = 0; t < L1; ++t) {
    if (t >= len) break;
    u = stepAK(a, krf, u, zr[t]);
    out[(size_t)(s0_ + t)*16 + r] = u;
  }
}

extern "C" void kernel_launch(void* const* d_in, const int* in_sizes, int n_in,
                              void* d_out, int out_size, void* d_ws, size_t ws_size,
                              hipStream_t stream) {
  const float* z  = (const float*)d_in[0];
  const float* Fg = (const float*)d_in[1];
  const float* Qg = (const float*)d_in[3];
  const float* Rg = (const float*)d_in[4];
  float* out = (float*)d_out;
  float* ws  = (float*)d_ws;

  kf_ricc<<<1, 64, 0, stream>>>(Fg, Qg, Rg, ws);
  const size_t need = (size_t)(OFF_UE + NCHUNK*16) * sizeof(float);
  if (ws_size >= need) {
    kf_scanA<1><<<NBLKS, 256, 0, stream>>>(z, Fg, ws, out);
    kf_winscanE<<<NBLKW, 256, 0, stream>>>(z, ws, out);
  } else {
    kf_scanA<0><<<NBLKS, 256, 0, stream>>>(z, Fg, ws, out);
    kf_win<<<NBLKW, 256, 0, stream>>>(ws, out);
    kf_scanE<<<NBLKW, 256, 0, stream>>>(z, ws, out);
  }
}